// Round 13
// baseline (938.131 us; speedup 1.0000x reference)
//
#include <hip/hip_runtime.h>
#include <math.h>

#define S_LEN 2048
#define NH 16
#define HDIM 64
#define BATCH 2
#define BHC 32          // BATCH*NH
#define KK 409          // int(2048 * (1.0 - 0.8)) per reference float math
#define DMODEL 1024

typedef __attribute__((ext_vector_type(8))) short bf16x8;   // 8 bf16 in 4 VGPRs
typedef __attribute__((ext_vector_type(4))) float f32x4;

#define SC_STR 1032     // fp32 half-score row stride (chunked exchange)
#define P_STR  2056     // bf16 P row stride (16B-aligned rows)
#define T_STR  40       // bf16 LDS tile row stride: 80 B, 16B-aligned, 2-way free

__device__ __forceinline__ unsigned f2ord(float f) {
    unsigned u = __float_as_uint(f);
    return (u & 0x80000000u) ? ~u : (u | 0x80000000u);
}
__device__ __forceinline__ float ord2f(unsigned v) {
    unsigned u = (v & 0x80000000u) ? (v & 0x7fffffffu) : ~v;
    return __uint_as_float(u);
}
__device__ __forceinline__ unsigned short f2bf(float f) {   // RNE
    unsigned u = __float_as_uint(f);
    u += 0x7fffu + ((u >> 16) & 1u);
    return (unsigned short)(u >> 16);
}
__device__ __forceinline__ float bf2f(unsigned short h) {
    return __uint_as_float(((unsigned)h) << 16);
}

// ---------------------------------------------------------------------------
// fp32 -> bf16 hi/lo split (vectorized float4 / ushort4), n4 = elements/4
// ---------------------------------------------------------------------------
__global__ __launch_bounds__(256)
void split32(const float* __restrict__ in, unsigned short* __restrict__ hi,
             unsigned short* __restrict__ lo, int n4)
{
    const int i = blockIdx.x * 256 + threadIdx.x;
    if (i < n4) {
        const float4 v = ((const float4*)in)[i];
        ushort4 h, l;
        h.x = f2bf(v.x); l.x = f2bf(v.x - bf2f(h.x));
        h.y = f2bf(v.y); l.y = f2bf(v.y - bf2f(h.y));
        h.z = f2bf(v.z); l.z = f2bf(v.z - bf2f(h.z));
        h.w = f2bf(v.w); l.w = f2bf(v.w - bf2f(h.w));
        ((ushort4*)hi)[i] = h;
        ((ushort4*)lo)[i] = l;
    }
}

// ---------------------------------------------------------------------------
// LDS-staged split-bf16 3-pass MFMA GEMM (R8 — banked).
//   C[m][n] = sum_k A[m][k]*B[n][k] + bias[n]
// ---------------------------------------------------------------------------
__global__ __launch_bounds__(256)
void gemm_mfma(const unsigned short* __restrict__ Ah, const unsigned short* __restrict__ Al,
               const unsigned short* __restrict__ Bh, const unsigned short* __restrict__ Bl,
               const float* __restrict__ bias, void* __restrict__ out0,
               void* __restrict__ out1, int mode)
{
    __shared__ __align__(16) unsigned short sAh[128 * T_STR];
    __shared__ __align__(16) unsigned short sAl[128 * T_STR];
    __shared__ __align__(16) unsigned short sBh[64 * T_STR];
    __shared__ __align__(16) unsigned short sBl[64 * T_STR];

    const int tid  = threadIdx.x;
    const int lane = tid & 63;
    const int w    = tid >> 6;
    const int q15  = lane & 15;
    const int quad = lane >> 4;
    const int n0b = blockIdx.x * 64;
    const int m0b = blockIdx.y * 128;
    const int wm = (w >> 1) * 64;
    const int wn = (w & 1) * 32;

    const int ar0 = tid >> 2, aks0 = (tid & 3) * 8;
    const int ar1 = (tid + 256) >> 2, aks1 = aks0;
    const int br = tid >> 2, bks = (tid & 3) * 8;

    const unsigned short* gAh0 = Ah + (size_t)(m0b + ar0) * 1024 + aks0;
    const unsigned short* gAh1 = Ah + (size_t)(m0b + ar1) * 1024 + aks1;
    const unsigned short* gAl0 = Al + (size_t)(m0b + ar0) * 1024 + aks0;
    const unsigned short* gAl1 = Al + (size_t)(m0b + ar1) * 1024 + aks1;
    const unsigned short* gBh = Bh + (size_t)(n0b + br) * 1024 + bks;
    const unsigned short* gBl = Bl + (size_t)(n0b + br) * 1024 + bks;

    f32x4 acc[4][2];
#pragma unroll
    for (int mt = 0; mt < 4; ++mt)
#pragma unroll
        for (int nt = 0; nt < 2; ++nt) acc[mt][nt] = (f32x4){0.f, 0.f, 0.f, 0.f};

#pragma unroll 1
    for (int k0 = 0; k0 < 1024; k0 += 32) {
        const bf16x8 vah0 = *(const bf16x8*)(gAh0 + k0);
        const bf16x8 vah1 = *(const bf16x8*)(gAh1 + k0);
        const bf16x8 val0 = *(const bf16x8*)(gAl0 + k0);
        const bf16x8 val1 = *(const bf16x8*)(gAl1 + k0);
        const bf16x8 vbh  = *(const bf16x8*)(gBh + k0);
        const bf16x8 vbl  = *(const bf16x8*)(gBl + k0);
        __syncthreads();
        *(bf16x8*)(sAh + ar0 * T_STR + aks0) = vah0;
        *(bf16x8*)(sAh + ar1 * T_STR + aks1) = vah1;
        *(bf16x8*)(sAl + ar0 * T_STR + aks0) = val0;
        *(bf16x8*)(sAl + ar1 * T_STR + aks1) = val1;
        *(bf16x8*)(sBh + br * T_STR + bks) = vbh;
        *(bf16x8*)(sBl + br * T_STR + bks) = vbl;
        __syncthreads();

        bf16x8 fbh[2], fbl[2];
#pragma unroll
        for (int nt = 0; nt < 2; ++nt) {
            fbh[nt] = *(const bf16x8*)(sBh + (wn + nt * 16 + q15) * T_STR + quad * 8);
            fbl[nt] = *(const bf16x8*)(sBl + (wn + nt * 16 + q15) * T_STR + quad * 8);
        }
#pragma unroll
        for (int mt = 0; mt < 4; ++mt) {
            const bf16x8 fah = *(const bf16x8*)(sAh + (wm + mt * 16 + q15) * T_STR + quad * 8);
            const bf16x8 fal = *(const bf16x8*)(sAl + (wm + mt * 16 + q15) * T_STR + quad * 8);
#pragma unroll
            for (int nt = 0; nt < 2; ++nt) {
                acc[mt][nt] = __builtin_amdgcn_mfma_f32_16x16x32_bf16(fah, fbh[nt], acc[mt][nt], 0, 0, 0);
                acc[mt][nt] = __builtin_amdgcn_mfma_f32_16x16x32_bf16(fah, fbl[nt], acc[mt][nt], 0, 0, 0);
                acc[mt][nt] = __builtin_amdgcn_mfma_f32_16x16x32_bf16(fal, fbh[nt], acc[mt][nt], 0, 0, 0);
            }
        }
    }

#pragma unroll
    for (int nt = 0; nt < 2; ++nt) {
        const int n = n0b + wn + nt * 16 + q15;
        const float bv = bias[n];
#pragma unroll
        for (int mt = 0; mt < 4; ++mt) {
            const int mb = m0b + wm + mt * 16 + quad * 4;
#pragma unroll
            for (int rg = 0; rg < 4; ++rg) {
                const int m = mb + rg;
                const float o = acc[mt][nt][rg] + bv;
                if (mode == 0) {
                    ((float*)out0)[(size_t)m * 1024 + n] = o;
                } else {
                    const int b = m >> 11, s = m & 2047;
                    const int h = n >> 6, hd = n & 63;
                    const size_t base = ((size_t)((b * NH + h) * S_LEN + s)) * HDIM + hd;
                    if (mode == 3) {
                        ((unsigned short*)out0)[base] = f2bf(o);
                    } else {
                        const unsigned short oh = f2bf(o);
                        ((unsigned short*)out0)[base] = oh;
                        ((unsigned short*)out1)[base] = f2bf(o - bf2f(oh));
                    }
                }
            }
        }
    }
}

// ---------------------------------------------------------------------------
// V bf16 [bh][s][64] -> Vt bf16 [bh][64][2048]  (B-operand layout for PV MFMA)
// ---------------------------------------------------------------------------
__global__ __launch_bounds__(256)
void transpose_v16(const unsigned short* __restrict__ V, unsigned short* __restrict__ Vt)
{
    __shared__ unsigned short t[64][72];
    const int tid = threadIdx.x;
    const int s0 = blockIdx.x * 64;
    const int bh = blockIdx.y;
    const unsigned short* Vb = V + (size_t)bh * S_LEN * HDIM;
#pragma unroll
    for (int i = 0; i < 4; ++i) {
        const int f = tid + i * 256;
        const int s = f >> 4;
        const int hq = (f & 15) * 4;
        const ushort4 v = *(const ushort4*)(Vb + (size_t)(s0 + s) * HDIM + hq);
        t[s][hq + 0] = v.x; t[s][hq + 1] = v.y; t[s][hq + 2] = v.z; t[s][hq + 3] = v.w;
    }
    __syncthreads();
    unsigned short* Vtb = Vt + (size_t)bh * HDIM * S_LEN;
#pragma unroll
    for (int i = 0; i < 4; ++i) {
        const int f = tid + i * 256;
        const int hd = f >> 4;
        const int sq = (f & 15) * 4;
        ushort4 v;
        v.x = t[sq + 0][hd]; v.y = t[sq + 1][hd];
        v.z = t[sq + 2][hd]; v.w = t[sq + 3][hd];
        *(ushort4*)(Vtb + (size_t)hd * S_LEN + s0 + sq) = v;
    }
}

// ---------------------------------------------------------------------------
// min over {u[i] >= X} (wave-wide), used when rank-count exits at cnt==K.
// ---------------------------------------------------------------------------
__device__ __forceinline__ unsigned minred(const unsigned* u, unsigned X)
{
    unsigned mn = 0xffffffffu;
#pragma unroll
    for (int i = 0; i < 32; ++i) {
        const unsigned v = (u[i] >= X) ? u[i] : 0xffffffffu;
        mn = v < mn ? v : mn;
    }
#pragma unroll
    for (int off = 32; off >= 1; off >>= 1) {
        const unsigned o = (unsigned)__shfl_xor((int)mn, off);
        mn = o < mn ? o : mn;
    }
    return mn;
}

// ---------------------------------------------------------------------------
// Fused attention — R12 structure (R8 family, four-times-passing) with
// latency-chain optimizations only:
//  * FUSED 2-row rank-count select: both rows' independent chains share each
//    pass -> pass latency paid once for two rows. T-evolution per row is
//    bit-identical to the serial version (exact keep-set {u >= T}).
//  * Vt prefetch (8 frags) issued before select, drains behind it.
//  * phase-1 K-load unroll 4.
// DO NOT make u0/u1 register-resident (R6 failed post-timing validation).
// Scratch u (~0.7 GB FETCH) proven NOT the limiter (R9/R11 removed it, slower).
// ---------------------------------------------------------------------------
__global__ __launch_bounds__(512, 4)
void attn_kernel(const unsigned short* __restrict__ Qh, const unsigned short* __restrict__ Ql,
                 const unsigned short* __restrict__ Kh, const unsigned short* __restrict__ Kl,
                 const unsigned short* __restrict__ Vt,
                 unsigned short* __restrict__ AOh, unsigned short* __restrict__ AOl)
{
    extern __shared__ __align__(16) char smem[];
    float* sc = (float*)smem;                       // [16][SC_STR] chunk, 66048 B
    unsigned short* P = (unsigned short*)smem;      // overlay [16][P_STR], 65792 B
    float* Opart = (float*)smem;                    // overlay [8][16][64], 32768 B

    const int tid  = threadIdx.x;
    const int lane = tid & 63;
    const int w    = tid >> 6;
    const int q15  = lane & 15;
    const int quad = lane >> 4;
    const int l5   = lane >> 5;       // 0..1
    const int l31  = lane & 31;       // 0..31

    // XCD swizzle: 4 heads per XCD -> K+V working set ~2.5 MB, fits 4 MB L2
    const int blk = blockIdx.x;
    const int bh  = (blk & 7) * 4 + ((blk >> 3) & 3);
    const int q0  = (blk >> 5) * 16;

    // ---- Q B-frags direct from global (held in regs for both chunks) ----
    const size_t qrow = ((size_t)bh * S_LEN + q0 + q15) * HDIM;
    const bf16x8 bqh0 = *(const bf16x8*)(Qh + qrow + quad * 8);
    const bf16x8 bqh1 = *(const bf16x8*)(Qh + qrow + 32 + quad * 8);
    const bf16x8 bql0 = *(const bf16x8*)(Ql + qrow + quad * 8);
    const bf16x8 bql1 = *(const bf16x8*)(Ql + qrow + 32 + quad * 8);

    const size_t kbase = (size_t)bh * S_LEN * HDIM;
    const int r0 = 2 * w, r1 = 2 * w + 1;
    unsigned u0[32], u1[32];

    // ---- phase 1: two key-chunks through the half-size exchange buffer ----
#pragma unroll 1
    for (int half = 0; half < 2; ++half) {
        f32x4 acc[8];
#pragma unroll 4
        for (int t = 0; t < 8; ++t) {
            const int key = w * 256 + half * 128 + t * 16 + q15;   // A-frag m
            const unsigned short* kh = Kh + kbase + (size_t)key * HDIM + quad * 8;
            const unsigned short* kl = Kl + kbase + (size_t)key * HDIM + quad * 8;
            const bf16x8 akh0 = *(const bf16x8*)(kh);
            const bf16x8 akh1 = *(const bf16x8*)(kh + 32);
            const bf16x8 akl0 = *(const bf16x8*)(kl);
            const bf16x8 akl1 = *(const bf16x8*)(kl + 32);
            f32x4 c = {0.f, 0.f, 0.f, 0.f};
            c = __builtin_amdgcn_mfma_f32_16x16x32_bf16(akh0, bqh0, c, 0, 0, 0);
            c = __builtin_amdgcn_mfma_f32_16x16x32_bf16(akh1, bqh1, c, 0, 0, 0);
            c = __builtin_amdgcn_mfma_f32_16x16x32_bf16(akh0, bql0, c, 0, 0, 0);
            c = __builtin_amdgcn_mfma_f32_16x16x32_bf16(akh1, bql1, c, 0, 0, 0);
            c = __builtin_amdgcn_mfma_f32_16x16x32_bf16(akl0, bqh0, c, 0, 0, 0);
            c = __builtin_amdgcn_mfma_f32_16x16x32_bf16(akl1, bqh1, c, 0, 0, 0);
            acc[t] = c * 0.125f;
        }
        if (half) __syncthreads();   // chunk-A reads complete before overwrite
        // C-layout: col=lane&15=q, row-in-tile=quad*4+reg=key
        // sc col c = w*128 + t*16 + quad*4 (+reg)  ->  key = (c>>7)*256 + half*128 + (c&127)
#pragma unroll
        for (int t = 0; t < 8; ++t)
            *(f32x4*)(sc + q15 * SC_STR + w * 128 + t * 16 + quad * 4) = acc[t];
        __syncthreads();
        // vectorized read of both owned rows' half: 4x ds_read_b128 each.
        // u[half*16+4i+cc] <-> key = (2i+l5)*256 + half*128 + l31*4 + cc
        unsigned* d0 = u0 + half * 16;
        unsigned* d1 = u1 + half * 16;
#pragma unroll
        for (int i = 0; i < 4; ++i) {
            const f32x4 v0 = *(const f32x4*)(sc + r0 * SC_STR + i * 256 + lane * 4);
            d0[4 * i + 0] = f2ord(v0[0]); d0[4 * i + 1] = f2ord(v0[1]);
            d0[4 * i + 2] = f2ord(v0[2]); d0[4 * i + 3] = f2ord(v0[3]);
            const f32x4 v1 = *(const f32x4*)(sc + r1 * SC_STR + i * 256 + lane * 4);
            d1[4 * i + 0] = f2ord(v1[0]); d1[4 * i + 1] = f2ord(v1[1]);
            d1[4 * i + 2] = f2ord(v1[2]); d1[4 * i + 3] = f2ord(v1[3]);
        }
    }
    __syncthreads();   // all chunk reads done; sc region is dead -> P region live

    // ---- Vt prefetch: independent of select, drains behind it ----
    const size_t vtb = (size_t)bh * HDIM * S_LEN;
    bf16x8 vpre[8];
#pragma unroll
    for (int ks = 0; ks < 2; ++ks)
#pragma unroll
        for (int ht = 0; ht < 4; ++ht) {
            const int key0 = w * 256 + ks * 32 + quad * 8;
            vpre[ks * 4 + ht] = *(const bf16x8*)(Vt + vtb + (size_t)(ht * 16 + q15) * S_LEN + key0);
        }

    // ---- phase 2a: FUSED 2-row rank-count select (shared pass latency) ----
    unsigned res0, res1;
    {
        unsigned T0 = 0, T1 = 0;
        int done = 0;
#pragma unroll 1
        for (int b = 31; b >= 0; --b) {
            const unsigned X0 = T0 | (1u << b);
            const unsigned X1 = T1 | (1u << b);
            int c0 = 0, c1 = 0;
#pragma unroll
            for (int i = 0; i < 32; ++i) {
                c0 += __builtin_popcountll(__ballot(u0[i] >= X0));
                c1 += __builtin_popcountll(__ballot(u1[i] >= X1));
            }
            if (!(done & 1) && c0 >= KK) { T0 = X0; if (c0 == KK) done |= 1; }
            if (!(done & 2) && c1 >= KK) { T1 = X1; if (c1 == KK) done |= 2; }
            if (done == 3) break;
        }
        res0 = (done & 1) ? minred(u0, T0) : T0;
        res1 = (done & 2) ? minred(u1, T1) : T1;
    }

    // ---- row maxes (fused) ----
    unsigned um0 = 0, um1 = 0;
#pragma unroll
    for (int i = 0; i < 32; ++i) {
        um0 = u0[i] > um0 ? u0[i] : um0;
        um1 = u1[i] > um1 ? u1[i] : um1;
    }
#pragma unroll
    for (int off = 32; off >= 1; off >>= 1) {
        const unsigned o0 = (unsigned)__shfl_xor((int)um0, off);
        um0 = o0 > um0 ? o0 : um0;
        const unsigned o1 = (unsigned)__shfl_xor((int)um1, off);
        um1 = o1 > um1 ? o1 : um1;
    }
    const float mx0 = ord2f(um0), mx1 = ord2f(um1);

    // ---- phase 2b: exp over kept set -> P (bf16), 2 rows/wave ----
    float invd[2];
#pragma unroll 1
    for (int rr = 0; rr < 2; ++rr) {
        const unsigned* u = rr ? u1 : u0;
        const int r = rr ? r1 : r0;
        const unsigned T = rr ? res1 : res0;
        const float mx = rr ? mx1 : mx0;
        float lsum = 0.f;
        unsigned short* Pr = P + r * P_STR;
#pragma unroll
        for (int h = 0; h < 2; ++h) {
#pragma unroll
            for (int i = 0; i < 4; ++i) {
                const unsigned a0 = u[h * 16 + 4 * i + 0];
                const unsigned a1 = u[h * 16 + 4 * i + 1];
                const unsigned a2 = u[h * 16 + 4 * i + 2];
                const unsigned a3 = u[h * 16 + 4 * i + 3];
                const float e0 = (a0 >= T) ? __expf(ord2f(a0) - mx) : 0.f;
                const float e1 = (a1 >= T) ? __expf(ord2f(a1) - mx) : 0.f;
                const float e2 = (a2 >= T) ? __expf(ord2f(a2) - mx) : 0.f;
                const float e3 = (a3 >= T) ? __expf(ord2f(a3) - mx) : 0.f;
                ushort4 pk;
                pk.x = f2bf(e0); pk.y = f2bf(e1); pk.z = f2bf(e2); pk.w = f2bf(e3);
                const int key = (2 * i + l5) * 256 + h * 128 + l31 * 4;
                *(ushort4*)(Pr + key) = pk;   // 8 B ds_write_b64
                lsum += e0 + e1 + e2 + e3;
            }
        }
#pragma unroll
        for (int off = 32; off >= 1; off >>= 1) lsum += __shfl_xor(lsum, off);
        invd[rr] = 1.f / lsum;
    }
    __syncthreads();   // all P visible

    // ---- phase 3: dense PV via bf16 MFMA, wave w keys [256w,256w+256) ----
    {
        f32x4 oacc[4];
#pragma unroll
        for (int ht = 0; ht < 4; ++ht) oacc[ht] = (f32x4){0.f, 0.f, 0.f, 0.f};
#pragma unroll
        for (int ks = 0; ks < 8; ++ks) {
            const int key0 = w * 256 + ks * 32 + quad * 8;
            const bf16x8 ap = *(const bf16x8*)(P + q15 * P_STR + key0);  // A[m=q][k=key]
#pragma unroll
            for (int ht = 0; ht < 4; ++ht) {
                const int hd = ht * 16 + q15;                            // B[k=key][n=hd]
                const bf16x8 bv = (ks < 2) ? vpre[ks * 4 + ht]
                                           : *(const bf16x8*)(Vt + vtb + (size_t)hd * S_LEN + key0);
                oacc[ht] = __builtin_amdgcn_mfma_f32_16x16x32_bf16(ap, bv, oacc[ht], 0, 0, 0);
            }
        }
        __syncthreads();   // all P reads done; P region dead -> Opart live
        // D[m=q][n=hd]: col=lane&15=hd-in-tile, row=quad*4+reg=q
#pragma unroll
        for (int ht = 0; ht < 4; ++ht)
#pragma unroll
            for (int rg = 0; rg < 4; ++rg)
                Opart[w * 1024 + (quad * 4 + rg) * 64 + ht * 16 + q15] = oacc[ht][rg];
    }
    __syncthreads();

    // ---- final: reduce 8 partials, scale, write AO as bf16 hi/lo ----
    {
        float s0 = 0.f, s1 = 0.f;
#pragma unroll
        for (int ww = 0; ww < 8; ++ww) {
            s0 += Opart[ww * 1024 + r0 * 64 + lane];
            s1 += Opart[ww * 1024 + r1 * 64 + lane];
        }
        const int b = bh >> 4, h = bh & 15;
        const float o0 = s0 * invd[0];
        const float o1 = s1 * invd[1];
        const size_t i0 = ((size_t)(b * S_LEN + q0 + r0)) * DMODEL + h * HDIM + lane;
        const size_t i1 = ((size_t)(b * S_LEN + q0 + r1)) * DMODEL + h * HDIM + lane;
        const unsigned short h0 = f2bf(o0), h1 = f2bf(o1);
        AOh[i0] = h0; AOl[i0] = f2bf(o0 - bf2f(h0));
        AOh[i1] = h1; AOl[i1] = f2bf(o1 - bf2f(h1));
    }
}

// ---------------------------------------------------------------------------
extern "C" void kernel_launch(void* const* d_in, const int* in_sizes, int n_in,
                              void* d_out, int out_size, void* d_ws, size_t ws_size,
                              hipStream_t stream)
{
    const float* X  = (const float*)d_in[0];
    const float* Wq = (const float*)d_in[1];
    const float* bq = (const float*)d_in[2];
    const float* Wk = (const float*)d_in[3];
    const float* bk = (const float*)d_in[4];
    const float* Wv = (const float*)d_in[5];
    const float* bv = (const float*)d_in[6];
    const float* Wo = (const float*)d_in[7];
    const float* bo = (const float*)d_in[8];

    char* p = (char*)d_ws;
    const size_t NEL = (size_t)BHC * S_LEN * HDIM;   // 4,194,304
    unsigned short* Q16h = (unsigned short*)p; p += NEL * 2;
    unsigned short* Q16l = (unsigned short*)p; p += NEL * 2;
    unsigned short* K16h = (unsigned short*)p; p += NEL * 2;
    unsigned short* K16l = (unsigned short*)p; p += NEL * 2;
    unsigned short* Vb16 = (unsigned short*)p; p += NEL * 2;
    unsigned short* Vt16 = (unsigned short*)p; p += NEL * 2;
    unsigned short* Xh   = (unsigned short*)p; p += NEL * 2;
    unsigned short* Xl   = (unsigned short*)p; p += NEL * 2;
    unsigned short* AOh  = (unsigned short*)p; p += NEL * 2;
    unsigned short* AOl  = (unsigned short*)p; p += NEL * 2;
    unsigned short* Wqh  = (unsigned short*)p; p += DMODEL * DMODEL * 2;
    unsigned short* Wql  = (unsigned short*)p; p += DMODEL * DMODEL * 2;
    unsigned short* Wkh  = (unsigned short*)p; p += DMODEL * DMODEL * 2;
    unsigned short* Wkl  = (unsigned short*)p; p += DMODEL * DMODEL * 2;
    unsigned short* Wvh  = (unsigned short*)p; p += DMODEL * DMODEL * 2;
    unsigned short* Wvl  = (unsigned short*)p; p += DMODEL * DMODEL * 2;
    unsigned short* Woh  = (unsigned short*)p; p += DMODEL * DMODEL * 2;
    unsigned short* Wol  = (unsigned short*)p; p += DMODEL * DMODEL * 2;

    const int attn_lds = 16 * SC_STR * 4;   // 66,048 B
    hipFuncSetAttribute((const void*)attn_kernel,
                        hipFuncAttributeMaxDynamicSharedMemorySize, attn_lds);

    const int X4 = (int)(NEL / 4);                 // 1,048,576
    const int W4 = DMODEL * DMODEL / 4;            //   262,144

    // ---- input splits ----
    split32<<<(X4 + 255) / 256, 256, 0, stream>>>(X,  Xh,  Xl,  X4);
    split32<<<(W4 + 255) / 256, 256, 0, stream>>>(Wq, Wqh, Wql, W4);
    split32<<<(W4 + 255) / 256, 256, 0, stream>>>(Wk, Wkh, Wkl, W4);
    split32<<<(W4 + 255) / 256, 256, 0, stream>>>(Wv, Wvh, Wvl, W4);
    split32<<<(W4 + 255) / 256, 256, 0, stream>>>(Wo, Woh, Wol, W4);

    // ---- projections (LDS-staged MFMA split-bf16): tiles 128m x 64n ----
    const dim3 ggrid(16, 32, 1);
    gemm_mfma<<<ggrid, 256, 0, stream>>>(Xh, Xl, Wqh, Wql, bq, Q16h, Q16l, 2);
    gemm_mfma<<<ggrid, 256, 0, stream>>>(Xh, Xl, Wkh, Wkl, bk, K16h, K16l, 2);
    gemm_mfma<<<ggrid, 256, 0, stream>>>(Xh, Xl, Wvh, Wvl, bv, Vb16, nullptr, 3);
    transpose_v16<<<dim3(32, 32, 1), 256, 0, stream>>>(Vb16, Vt16);

    // ---- fused attention (fused select + Vt prefetch) ----
    attn_kernel<<<4096, 512, attn_lds, stream>>>(Q16h, Q16l, K16h, K16l, Vt16, AOh, AOl);

    // ---- output projection ----
    gemm_mfma<<<ggrid, 256, 0, stream>>>(AOh, AOl, Woh, Wol, bo, d_out, nullptr, 0);
}

// Round 14
// 889.790 us; speedup vs baseline: 1.0543x; 1.0543x over previous
//
#include <hip/hip_runtime.h>
#include <math.h>

#define S_LEN 2048
#define NH 16
#define HDIM 64
#define BATCH 2
#define BHC 32          // BATCH*NH
#define KK 409          // int(2048 * (1.0 - 0.8)) per reference float math
#define DMODEL 1024

typedef __attribute__((ext_vector_type(8))) short bf16x8;   // 8 bf16 in 4 VGPRs
typedef __attribute__((ext_vector_type(4))) float f32x4;

#define SC_STRQ 520     // fp32 quarter-score row stride (512 + 8 pad)
#define P_STRH  1032    // bf16 P-half row stride (2064 B rows, 16B-aligned)
#define T_STR   40      // bf16 LDS tile row stride for gemm (16B-aligned, 2-way free)

__device__ __forceinline__ unsigned f2ord(float f) {
    unsigned u = __float_as_uint(f);
    return (u & 0x80000000u) ? ~u : (u | 0x80000000u);
}
__device__ __forceinline__ float ord2f(unsigned v) {
    unsigned u = (v & 0x80000000u) ? (v & 0x7fffffffu) : ~v;
    return __uint_as_float(u);
}
__device__ __forceinline__ unsigned short f2bf(float f) {   // RNE
    unsigned u = __float_as_uint(f);
    u += 0x7fffu + ((u >> 16) & 1u);
    return (unsigned short)(u >> 16);
}
__device__ __forceinline__ float bf2f(unsigned short h) {
    return __uint_as_float(((unsigned)h) << 16);
}

// ---------------------------------------------------------------------------
// fp32 -> bf16 hi/lo split (vectorized float4 / ushort4), n4 = elements/4
// ---------------------------------------------------------------------------
__global__ __launch_bounds__(256)
void split32(const float* __restrict__ in, unsigned short* __restrict__ hi,
             unsigned short* __restrict__ lo, int n4)
{
    const int i = blockIdx.x * 256 + threadIdx.x;
    if (i < n4) {
        const float4 v = ((const float4*)in)[i];
        ushort4 h, l;
        h.x = f2bf(v.x); l.x = f2bf(v.x - bf2f(h.x));
        h.y = f2bf(v.y); l.y = f2bf(v.y - bf2f(h.y));
        h.z = f2bf(v.z); l.z = f2bf(v.z - bf2f(h.z));
        h.w = f2bf(v.w); l.w = f2bf(v.w - bf2f(h.w));
        ((ushort4*)hi)[i] = h;
        ((ushort4*)lo)[i] = l;
    }
}

// ---------------------------------------------------------------------------
// LDS-staged split-bf16 3-pass MFMA GEMM (R8 — banked).
//   C[m][n] = sum_k A[m][k]*B[n][k] + bias[n]
// ---------------------------------------------------------------------------
__global__ __launch_bounds__(256)
void gemm_mfma(const unsigned short* __restrict__ Ah, const unsigned short* __restrict__ Al,
               const unsigned short* __restrict__ Bh, const unsigned short* __restrict__ Bl,
               const float* __restrict__ bias, void* __restrict__ out0,
               void* __restrict__ out1, int mode)
{
    __shared__ __align__(16) unsigned short sAh[128 * T_STR];
    __shared__ __align__(16) unsigned short sAl[128 * T_STR];
    __shared__ __align__(16) unsigned short sBh[64 * T_STR];
    __shared__ __align__(16) unsigned short sBl[64 * T_STR];

    const int tid  = threadIdx.x;
    const int lane = tid & 63;
    const int w    = tid >> 6;
    const int q15  = lane & 15;
    const int quad = lane >> 4;
    const int n0b = blockIdx.x * 64;
    const int m0b = blockIdx.y * 128;
    const int wm = (w >> 1) * 64;
    const int wn = (w & 1) * 32;

    const int ar0 = tid >> 2, aks0 = (tid & 3) * 8;
    const int ar1 = (tid + 256) >> 2, aks1 = aks0;
    const int br = tid >> 2, bks = (tid & 3) * 8;

    const unsigned short* gAh0 = Ah + (size_t)(m0b + ar0) * 1024 + aks0;
    const unsigned short* gAh1 = Ah + (size_t)(m0b + ar1) * 1024 + aks1;
    const unsigned short* gAl0 = Al + (size_t)(m0b + ar0) * 1024 + aks0;
    const unsigned short* gAl1 = Al + (size_t)(m0b + ar1) * 1024 + aks1;
    const unsigned short* gBh = Bh + (size_t)(n0b + br) * 1024 + bks;
    const unsigned short* gBl = Bl + (size_t)(n0b + br) * 1024 + bks;

    f32x4 acc[4][2];
#pragma unroll
    for (int mt = 0; mt < 4; ++mt)
#pragma unroll
        for (int nt = 0; nt < 2; ++nt) acc[mt][nt] = (f32x4){0.f, 0.f, 0.f, 0.f};

#pragma unroll 1
    for (int k0 = 0; k0 < 1024; k0 += 32) {
        const bf16x8 vah0 = *(const bf16x8*)(gAh0 + k0);
        const bf16x8 vah1 = *(const bf16x8*)(gAh1 + k0);
        const bf16x8 val0 = *(const bf16x8*)(gAl0 + k0);
        const bf16x8 val1 = *(const bf16x8*)(gAl1 + k0);
        const bf16x8 vbh  = *(const bf16x8*)(gBh + k0);
        const bf16x8 vbl  = *(const bf16x8*)(gBl + k0);
        __syncthreads();
        *(bf16x8*)(sAh + ar0 * T_STR + aks0) = vah0;
        *(bf16x8*)(sAh + ar1 * T_STR + aks1) = vah1;
        *(bf16x8*)(sAl + ar0 * T_STR + aks0) = val0;
        *(bf16x8*)(sAl + ar1 * T_STR + aks1) = val1;
        *(bf16x8*)(sBh + br * T_STR + bks) = vbh;
        *(bf16x8*)(sBl + br * T_STR + bks) = vbl;
        __syncthreads();

        bf16x8 fbh[2], fbl[2];
#pragma unroll
        for (int nt = 0; nt < 2; ++nt) {
            fbh[nt] = *(const bf16x8*)(sBh + (wn + nt * 16 + q15) * T_STR + quad * 8);
            fbl[nt] = *(const bf16x8*)(sBl + (wn + nt * 16 + q15) * T_STR + quad * 8);
        }
#pragma unroll
        for (int mt = 0; mt < 4; ++mt) {
            const bf16x8 fah = *(const bf16x8*)(sAh + (wm + mt * 16 + q15) * T_STR + quad * 8);
            const bf16x8 fal = *(const bf16x8*)(sAl + (wm + mt * 16 + q15) * T_STR + quad * 8);
#pragma unroll
            for (int nt = 0; nt < 2; ++nt) {
                acc[mt][nt] = __builtin_amdgcn_mfma_f32_16x16x32_bf16(fah, fbh[nt], acc[mt][nt], 0, 0, 0);
                acc[mt][nt] = __builtin_amdgcn_mfma_f32_16x16x32_bf16(fah, fbl[nt], acc[mt][nt], 0, 0, 0);
                acc[mt][nt] = __builtin_amdgcn_mfma_f32_16x16x32_bf16(fal, fbh[nt], acc[mt][nt], 0, 0, 0);
            }
        }
    }

#pragma unroll
    for (int nt = 0; nt < 2; ++nt) {
        const int n = n0b + wn + nt * 16 + q15;
        const float bv = bias[n];
#pragma unroll
        for (int mt = 0; mt < 4; ++mt) {
            const int mb = m0b + wm + mt * 16 + quad * 4;
#pragma unroll
            for (int rg = 0; rg < 4; ++rg) {
                const int m = mb + rg;
                const float o = acc[mt][nt][rg] + bv;
                if (mode == 0) {
                    ((float*)out0)[(size_t)m * 1024 + n] = o;
                } else {
                    const int b = m >> 11, s = m & 2047;
                    const int h = n >> 6, hd = n & 63;
                    const size_t base = ((size_t)((b * NH + h) * S_LEN + s)) * HDIM + hd;
                    if (mode == 3) {
                        ((unsigned short*)out0)[base] = f2bf(o);
                    } else {
                        const unsigned short oh = f2bf(o);
                        ((unsigned short*)out0)[base] = oh;
                        ((unsigned short*)out1)[base] = f2bf(o - bf2f(oh));
                    }
                }
            }
        }
    }
}

// ---------------------------------------------------------------------------
// V bf16 [bh][s][64] -> Vt bf16 [bh][64][2048]  (B-operand layout for PV MFMA)
// ---------------------------------------------------------------------------
__global__ __launch_bounds__(256)
void transpose_v16(const unsigned short* __restrict__ V, unsigned short* __restrict__ Vt)
{
    __shared__ unsigned short t[64][72];
    const int tid = threadIdx.x;
    const int s0 = blockIdx.x * 64;
    const int bh = blockIdx.y;
    const unsigned short* Vb = V + (size_t)bh * S_LEN * HDIM;
#pragma unroll
    for (int i = 0; i < 4; ++i) {
        const int f = tid + i * 256;
        const int s = f >> 4;
        const int hq = (f & 15) * 4;
        const ushort4 v = *(const ushort4*)(Vb + (size_t)(s0 + s) * HDIM + hq);
        t[s][hq + 0] = v.x; t[s][hq + 1] = v.y; t[s][hq + 2] = v.z; t[s][hq + 3] = v.w;
    }
    __syncthreads();
    unsigned short* Vtb = Vt + (size_t)bh * HDIM * S_LEN;
#pragma unroll
    for (int i = 0; i < 4; ++i) {
        const int f = tid + i * 256;
        const int hd = f >> 4;
        const int sq = (f & 15) * 4;
        ushort4 v;
        v.x = t[sq + 0][hd]; v.y = t[sq + 1][hd];
        v.z = t[sq + 2][hd]; v.w = t[sq + 3][hd];
        *(ushort4*)(Vtb + (size_t)hd * S_LEN + s0 + sq) = v;
    }
}

// ---------------------------------------------------------------------------
// Exact 409th-largest over 2048 ordered uints held as u[32] per lane.
// Rank-count binary search (R10/R12-proven). Keep set {u >= T} incl. ties.
// Runtime-pointer arg preserved (R8-family passing structure).
// ---------------------------------------------------------------------------
__device__ __forceinline__ unsigned radix_select(const unsigned* u)
{
    unsigned T = 0;
#pragma unroll 1
    for (int b = 31; b >= 0; --b) {
        const unsigned X = T | (1u << b);
        int cnt = 0;
#pragma unroll
        for (int i = 0; i < 32; ++i)
            cnt += __builtin_popcountll(__ballot(u[i] >= X));
        if (cnt >= KK) {
            T = X;
            if (cnt == KK) {   // answer = min over {u >= X}
                unsigned mn = 0xffffffffu;
#pragma unroll
                for (int i = 0; i < 32; ++i) {
                    const unsigned v = (u[i] >= X) ? u[i] : 0xffffffffu;
                    mn = v < mn ? v : mn;
                }
#pragma unroll
                for (int off = 32; off >= 1; off >>= 1) {
                    const unsigned o = (unsigned)__shfl_xor((int)mn, off);
                    mn = o < mn ? o : mn;
                }
                return mn;
            }
        }
    }
    return T;
}

// ---------------------------------------------------------------------------
// Fused attention v11 — R12 logic (same MFMA count, same serial rank-count
// selects, same PV total, bit-identical scores/keep-sets) with the LDS
// footprint quartered to raise occupancy 4 -> 8 waves/SIMD:
//  * score exchange in FOUR 64-col chunks through sc[16][520] (33,280 B)
//  * P chunked into 2 halves of [16][1032] bf16 (33,024 B, same region),
//    each half: exp+write -> barrier -> PV-half -> barrier; oacc carries
//    across halves in registers
//  * Opart [8][16][64] f32 (32,768 B) overlays the same region at the end
// R13's select-fusion and Vt-prefetch are REVERTED (both regressed: +spill).
// DO NOT make u0/u1 register-resident (R6 failed post-timing validation).
// u index map: u[qtr*8 + 4i + cc] <-> key = (4i+quad)*256 + qtr*64 + q15*4+cc
//   (i=0 -> keys 0..1023 = P-half 0; i=1 -> keys 1024..2047 = P-half 1)
// ---------------------------------------------------------------------------
__global__ __launch_bounds__(512, 8)
void attn_kernel(const unsigned short* __restrict__ Qh, const unsigned short* __restrict__ Ql,
                 const unsigned short* __restrict__ Kh, const unsigned short* __restrict__ Kl,
                 const unsigned short* __restrict__ Vt,
                 unsigned short* __restrict__ AOh, unsigned short* __restrict__ AOl)
{
    extern __shared__ __align__(16) char smem[];
    float* sc = (float*)smem;                       // [16][520] f32, 33,280 B
    unsigned short* P = (unsigned short*)smem;      // overlay [16][1032] bf16, 33,024 B
    float* Opart = (float*)smem;                    // overlay [8][16][64] f32, 32,768 B

    const int tid  = threadIdx.x;
    const int lane = tid & 63;
    const int w    = tid >> 6;
    const int q15  = lane & 15;
    const int quad = lane >> 4;

    // XCD swizzle: 4 heads per XCD -> K+V working set ~2.5 MB, fits 4 MB L2
    const int blk = blockIdx.x;
    const int bh  = (blk & 7) * 4 + ((blk >> 3) & 3);
    const int q0  = (blk >> 5) * 16;

    // ---- Q B-frags direct from global (held in regs throughout) ----
    const size_t qrow = ((size_t)bh * S_LEN + q0 + q15) * HDIM;
    const bf16x8 bqh0 = *(const bf16x8*)(Qh + qrow + quad * 8);
    const bf16x8 bqh1 = *(const bf16x8*)(Qh + qrow + 32 + quad * 8);
    const bf16x8 bql0 = *(const bf16x8*)(Ql + qrow + quad * 8);
    const bf16x8 bql1 = *(const bf16x8*)(Ql + qrow + 32 + quad * 8);

    const size_t kbase = (size_t)bh * S_LEN * HDIM;
    const int r0 = 2 * w, r1 = 2 * w + 1;
    unsigned u0[32], u1[32];

    // ---- phase 1: four key-quarters through the quarter-size buffer ----
#pragma unroll 1
    for (int qtr = 0; qtr < 4; ++qtr) {
        f32x4 acc[4];
#pragma unroll
        for (int t = 0; t < 4; ++t) {
            const int key = w * 256 + qtr * 64 + t * 16 + q15;   // A-frag m
            const unsigned short* kh = Kh + kbase + (size_t)key * HDIM + quad * 8;
            const unsigned short* kl = Kl + kbase + (size_t)key * HDIM + quad * 8;
            const bf16x8 akh0 = *(const bf16x8*)(kh);
            const bf16x8 akh1 = *(const bf16x8*)(kh + 32);
            const bf16x8 akl0 = *(const bf16x8*)(kl);
            const bf16x8 akl1 = *(const bf16x8*)(kl + 32);
            f32x4 c = {0.f, 0.f, 0.f, 0.f};
            c = __builtin_amdgcn_mfma_f32_16x16x32_bf16(akh0, bqh0, c, 0, 0, 0);
            c = __builtin_amdgcn_mfma_f32_16x16x32_bf16(akh1, bqh1, c, 0, 0, 0);
            c = __builtin_amdgcn_mfma_f32_16x16x32_bf16(akh0, bql0, c, 0, 0, 0);
            c = __builtin_amdgcn_mfma_f32_16x16x32_bf16(akh1, bql1, c, 0, 0, 0);
            c = __builtin_amdgcn_mfma_f32_16x16x32_bf16(akl0, bqh0, c, 0, 0, 0);
            c = __builtin_amdgcn_mfma_f32_16x16x32_bf16(akl1, bqh1, c, 0, 0, 0);
            acc[t] = c * 0.125f;
        }
        if (qtr) __syncthreads();   // prior quarter's reads complete
        // C-layout: col=lane&15=q, row-in-tile=quad*4+reg=key
#pragma unroll
        for (int t = 0; t < 4; ++t)
            *(f32x4*)(sc + q15 * SC_STRQ + w * 64 + t * 16 + quad * 4) = acc[t];
        __syncthreads();
        // read both owned rows' quarter: 2x ds_read_b128 each
        unsigned* d0 = u0 + qtr * 8;
        unsigned* d1 = u1 + qtr * 8;
#pragma unroll
        for (int i = 0; i < 2; ++i) {
            const f32x4 v0 = *(const f32x4*)(sc + r0 * SC_STRQ + i * 256 + lane * 4);
            d0[4 * i + 0] = f2ord(v0[0]); d0[4 * i + 1] = f2ord(v0[1]);
            d0[4 * i + 2] = f2ord(v0[2]); d0[4 * i + 3] = f2ord(v0[3]);
            const f32x4 v1 = *(const f32x4*)(sc + r1 * SC_STRQ + i * 256 + lane * 4);
            d1[4 * i + 0] = f2ord(v1[0]); d1[4 * i + 1] = f2ord(v1[1]);
            d1[4 * i + 2] = f2ord(v1[2]); d1[4 * i + 3] = f2ord(v1[3]);
        }
    }
    __syncthreads();   // sc dead everywhere -> P region reusable

    // ---- phase 2a: serial per-row rank-count select + row max (R12) ----
    unsigned Ts[2];
    float mxs[2];
#pragma unroll 1
    for (int rr = 0; rr < 2; ++rr) {
        const unsigned* u = rr ? u1 : u0;
        Ts[rr] = radix_select(u);
        unsigned umx = 0;
#pragma unroll
        for (int i = 0; i < 32; ++i) umx = u[i] > umx ? u[i] : umx;
#pragma unroll
        for (int off = 32; off >= 1; off >>= 1) {
            const unsigned o = (unsigned)__shfl_xor((int)umx, off);
            umx = o > umx ? o : umx;
        }
        mxs[rr] = ord2f(umx);
    }

    // ---- phase 2b/3: two P-halves, exp+write -> PV-half, oacc carries ----
    const size_t vtb = (size_t)bh * HDIM * S_LEN;
    float lsum[2] = {0.f, 0.f};
    f32x4 oacc[4];
#pragma unroll
    for (int ht = 0; ht < 4; ++ht) oacc[ht] = (f32x4){0.f, 0.f, 0.f, 0.f};

#pragma unroll 1
    for (int h = 0; h < 2; ++h) {
        // exp + write both rows' h-half entries (4 x ushort4 per row)
#pragma unroll 1
        for (int rr = 0; rr < 2; ++rr) {
            const unsigned* u = rr ? u1 : u0;
            const int r = rr ? r1 : r0;
            const unsigned T = Ts[rr];
            const float mx = mxs[rr];
            float ls = 0.f;
            unsigned short* Pr = P + r * P_STRH;
#pragma unroll
            for (int qtr = 0; qtr < 4; ++qtr) {
                const unsigned a0 = u[qtr * 8 + h * 4 + 0];
                const unsigned a1 = u[qtr * 8 + h * 4 + 1];
                const unsigned a2 = u[qtr * 8 + h * 4 + 2];
                const unsigned a3 = u[qtr * 8 + h * 4 + 3];
                const float e0 = (a0 >= T) ? __expf(ord2f(a0) - mx) : 0.f;
                const float e1 = (a1 >= T) ? __expf(ord2f(a1) - mx) : 0.f;
                const float e2 = (a2 >= T) ? __expf(ord2f(a2) - mx) : 0.f;
                const float e3 = (a3 >= T) ? __expf(ord2f(a3) - mx) : 0.f;
                ushort4 pk;
                pk.x = f2bf(e0); pk.y = f2bf(e1); pk.z = f2bf(e2); pk.w = f2bf(e3);
                // local key (within half) = quad*256 + qtr*64 + q15*4
                *(ushort4*)(Pr + quad * 256 + qtr * 64 + q15 * 4) = pk;
                ls += e0 + e1 + e2 + e3;
            }
            lsum[rr] += ls;
        }
        __syncthreads();   // this half's P visible
        // PV for this half: wave w covers local keys [128w, 128w+128)
#pragma unroll
        for (int ks = 0; ks < 4; ++ks) {
            const int lk0 = 128 * w + ks * 32 + quad * 8;
            const bf16x8 ap = *(const bf16x8*)(P + q15 * P_STRH + lk0);   // A[m=q][k]
#pragma unroll
            for (int ht = 0; ht < 4; ++ht) {
                const int hd = ht * 16 + q15;                             // B[k][n=hd]
                const bf16x8 bv = *(const bf16x8*)(Vt + vtb + (size_t)hd * S_LEN + h * 1024 + lk0);
                oacc[ht] = __builtin_amdgcn_mfma_f32_16x16x32_bf16(ap, bv, oacc[ht], 0, 0, 0);
            }
        }
        __syncthreads();   // this half's P reads done -> region reusable
    }

    // ---- Opart exchange + final reduce ----
    // D[m=q][n=hd]: col=lane&15=hd-in-tile, row=quad*4+reg=q
#pragma unroll
    for (int ht = 0; ht < 4; ++ht)
#pragma unroll
        for (int rg = 0; rg < 4; ++rg)
            Opart[w * 1024 + (quad * 4 + rg) * 64 + ht * 16 + q15] = oacc[ht][rg];
    __syncthreads();

    {
        float s0 = 0.f, s1 = 0.f;
#pragma unroll
        for (int off = 32; off >= 1; off >>= 1) {
            lsum[0] += __shfl_xor(lsum[0], off);
            lsum[1] += __shfl_xor(lsum[1], off);
        }
#pragma unroll
        for (int ww = 0; ww < 8; ++ww) {
            s0 += Opart[ww * 1024 + r0 * 64 + lane];
            s1 += Opart[ww * 1024 + r1 * 64 + lane];
        }
        const int b = bh >> 4, h = bh & 15;
        const float o0 = s0 / lsum[0];
        const float o1 = s1 / lsum[1];
        const size_t i0 = ((size_t)(b * S_LEN + q0 + r0)) * DMODEL + h * HDIM + lane;
        const size_t i1 = ((size_t)(b * S_LEN + q0 + r1)) * DMODEL + h * HDIM + lane;
        const unsigned short h0 = f2bf(o0), h1 = f2bf(o1);
        AOh[i0] = h0; AOl[i0] = f2bf(o0 - bf2f(h0));
        AOh[i1] = h1; AOl[i1] = f2bf(o1 - bf2f(h1));
    }
}

// ---------------------------------------------------------------------------
extern "C" void kernel_launch(void* const* d_in, const int* in_sizes, int n_in,
                              void* d_out, int out_size, void* d_ws, size_t ws_size,
                              hipStream_t stream)
{
    const float* X  = (const float*)d_in[0];
    const float* Wq = (const float*)d_in[1];
    const float* bq = (const float*)d_in[2];
    const float* Wk = (const float*)d_in[3];
    const float* bk = (const float*)d_in[4];
    const float* Wv = (const float*)d_in[5];
    const float* bv = (const float*)d_in[6];
    const float* Wo = (const float*)d_in[7];
    const float* bo = (const float*)d_in[8];

    char* p = (char*)d_ws;
    const size_t NEL = (size_t)BHC * S_LEN * HDIM;   // 4,194,304
    unsigned short* Q16h = (unsigned short*)p; p += NEL * 2;
    unsigned short* Q16l = (unsigned short*)p; p += NEL * 2;
    unsigned short* K16h = (unsigned short*)p; p += NEL * 2;
    unsigned short* K16l = (unsigned short*)p; p += NEL * 2;
    unsigned short* Vb16 = (unsigned short*)p; p += NEL * 2;
    unsigned short* Vt16 = (unsigned short*)p; p += NEL * 2;
    unsigned short* Xh   = (unsigned short*)p; p += NEL * 2;
    unsigned short* Xl   = (unsigned short*)p; p += NEL * 2;
    unsigned short* AOh  = (unsigned short*)p; p += NEL * 2;
    unsigned short* AOl  = (unsigned short*)p; p += NEL * 2;
    unsigned short* Wqh  = (unsigned short*)p; p += DMODEL * DMODEL * 2;
    unsigned short* Wql  = (unsigned short*)p; p += DMODEL * DMODEL * 2;
    unsigned short* Wkh  = (unsigned short*)p; p += DMODEL * DMODEL * 2;
    unsigned short* Wkl  = (unsigned short*)p; p += DMODEL * DMODEL * 2;
    unsigned short* Wvh  = (unsigned short*)p; p += DMODEL * DMODEL * 2;
    unsigned short* Wvl  = (unsigned short*)p; p += DMODEL * DMODEL * 2;
    unsigned short* Woh  = (unsigned short*)p; p += DMODEL * DMODEL * 2;
    unsigned short* Wol  = (unsigned short*)p; p += DMODEL * DMODEL * 2;

    const int attn_lds = 16 * SC_STRQ * 4;   // 33,280 B -> 4 blocks/CU
    hipFuncSetAttribute((const void*)attn_kernel,
                        hipFuncAttributeMaxDynamicSharedMemorySize, attn_lds);

    const int X4 = (int)(NEL / 4);                 // 1,048,576
    const int W4 = DMODEL * DMODEL / 4;            //   262,144

    // ---- input splits ----
    split32<<<(X4 + 255) / 256, 256, 0, stream>>>(X,  Xh,  Xl,  X4);
    split32<<<(W4 + 255) / 256, 256, 0, stream>>>(Wq, Wqh, Wql, W4);
    split32<<<(W4 + 255) / 256, 256, 0, stream>>>(Wk, Wkh, Wkl, W4);
    split32<<<(W4 + 255) / 256, 256, 0, stream>>>(Wv, Wvh, Wvl, W4);
    split32<<<(W4 + 255) / 256, 256, 0, stream>>>(Wo, Woh, Wol, W4);

    // ---- projections (LDS-staged MFMA split-bf16): tiles 128m x 64n ----
    const dim3 ggrid(16, 32, 1);
    gemm_mfma<<<ggrid, 256, 0, stream>>>(Xh, Xl, Wqh, Wql, bq, Q16h, Q16l, 2);
    gemm_mfma<<<ggrid, 256, 0, stream>>>(Xh, Xl, Wkh, Wkl, bk, K16h, K16l, 2);
    gemm_mfma<<<ggrid, 256, 0, stream>>>(Xh, Xl, Wvh, Wvl, bv, Vb16, nullptr, 3);
    transpose_v16<<<dim3(32, 32, 1), 256, 0, stream>>>(Vb16, Vt16);

    // ---- fused attention v11 (quarter-chunk exchange, 8 waves/SIMD) ----
    attn_kernel<<<4096, 512, attn_lds, stream>>>(Q16h, Q16l, K16h, K16l, Vt16, AOh, AOl);

    // ---- output projection ----
    gemm_mfma<<<ggrid, 256, 0, stream>>>(AOh, AOl, Woh, Wol, bo, d_out, nullptr, 0);
}